// Round 6
// baseline (343.249 us; speedup 1.0000x reference)
//
#include <hip/hip_runtime.h>

using u16 = unsigned short;
using u32 = unsigned int;
typedef __attribute__((ext_vector_type(8))) short bf16x8;
typedef __attribute__((ext_vector_type(4))) float f32x4;

// ---------- posit(8,1) round-to-nearest (float core, verified bit-exact on HW) ----------
__device__ __forceinline__ float posit_q(float x) {
    float a = __builtin_fabsf(x);
    u32 u = __float_as_uint(a);
    int logx = (int)(u >> 23) - 127;
    logx = logx < -60 ? -60 : (logx > 60 ? 60 : logx);
    float frac = __uint_as_float((u & 0x007fffffu) | 0x3f800000u);  // [1,2)
    int k = logx >> 1;                            // floor(logx/2), es=1
    int rl = (k >= 0) ? (k + 2) : (1 - k);        // regime length
    int fb = 6 - rl; fb = fb < 0 ? 0 : fb;        // fraction bits, <=4
    float step = (float)(1 << fb);
    float q = rintf(frac * step) * __uint_as_float((u32)(127 + logx - fb) << 23);
    q = fminf(fmaxf(q, 0x1p-12f), 0x1p12f);
    return (a > 0.0f) ? copysignf(q, x) : 0.0f;
}

__device__ __forceinline__ float b2f(u16 v) { return __uint_as_float((u32)v << 16); }
__device__ __forceinline__ u16 f2b(float f) { return (u16)(__float_as_uint(f) >> 16); }  // exact for posit values

// ---------- kernel 1: quantize weights ----------
// w2frag layout: [nt(4)][kc(9)][lane(64)][e(8)]; B[k][n], k=kc*32+(lane>>4)*8+e (ci), n=nt*16+(lane&15).
__global__ __launch_bounds__(256) void prep_kernel(
    const float* __restrict__ w1, const float* __restrict__ w2,
    const float* __restrict__ fw1, const float* __restrict__ fw2,
    float* __restrict__ w1q, u16* __restrict__ w2frag,
    u16* __restrict__ fc1wq, float* __restrict__ fc2wq) {
    int i = blockIdx.x * 256 + threadIdx.x;
    if (i < 288)  w1q[i]   = posit_q(w1[i]);
    if (i < 1280) fc2wq[i] = posit_q(fw2[i]);
    if (i < 18432) {
        int e = i & 7, lane = (i >> 3) & 63, c9 = i >> 9;
        int kc = c9 % 9, nt = c9 / 9;
        int n = nt * 16 + (lane & 15);
        int ci = ((lane >> 4) << 3) + e;
        w2frag[i] = f2b(posit_q(w2[n * 288 + ci * 9 + kc]));  // w2 flat [n][ci][kh][kw]
    }
    if (i < 1179648) fc1wq[i] = f2b(posit_q(fw1[i]));         // [n=128][k=9216]
}

// ---------- kernel 2: fused pq(x) + conv1 + relu + pq + conv2(MFMA) + bias + relu + pool + pq ----------
// Per block = one image. conv2: M=576 (pool-permuted), N=64, K=288.
// Wave mapping: wave -> (n-pair = wave&1, m-half = wave>>1). Each wave holds 18 B-frags
// (72 VGPRs — small enough for the allocator to keep resident) and loops 18 m-tiles:
// 1 ds_read_b128 feeds 2 MFMA. sH1 pixel stride 40 u16 (80 B, 16B-aligned, even bank spread).
#define H1S 40
__global__ __launch_bounds__(256, 2) void conv_fused_kernel(
    const float* __restrict__ x, const float* __restrict__ w1q, const float* __restrict__ b1,
    const u16* __restrict__ w2frag, const float* __restrict__ b2, u16* __restrict__ pooled) {
    __shared__ __align__(16) float sX[784];           // 3136 B
    __shared__ __align__(16) u16 sH1[676 * H1S];      // 54080 B
    __shared__ __align__(16) u16 sPool[64 * 152];     // 19456 B  (total 76672 B -> 2 blocks/CU)
    int img = blockIdx.x, tid = threadIdx.x;
    int wave = tid >> 6, lane = tid & 63;
    int col = lane & 15, quad = lane >> 4;

    // phase 0: load + pq input image (posit values are f32-exact)
    for (int i = tid; i < 784; i += 256) sX[i] = posit_q(x[(size_t)img * 784 + i]);

    // conv1 weights for this thread's oc pair (registers)
    int ocp = tid & 15;
    float wreg[18];
#pragma unroll
    for (int j = 0; j < 18; ++j) wreg[j] = w1q[ocp * 18 + j];
    float bias0 = b1[ocp * 2], bias1 = b1[ocp * 2 + 1];

    __syncthreads();

    // phase 1: conv1 (+bias+relu+pq) -> sH1. thread = (pixel-group pgrp, oc-pair ocp). Explicit fmaf.
    int pgrp = tid >> 4;
    for (int it = 0; it < 43; ++it) {
        int p = it * 16 + pgrp;
        if (p < 676) {
            int y = p / 26, xx = p - y * 26;
            const float* px = &sX[y * 28 + xx];
            float in9[9];
#pragma unroll
            for (int r = 0; r < 3; ++r)
#pragma unroll
                for (int c = 0; c < 3; ++c) in9[r * 3 + c] = px[r * 28 + c];
            float a0 = bias0, a1 = bias1;
#pragma unroll
            for (int j = 0; j < 9; ++j) {
                a0 = fmaf(wreg[j], in9[j], a0);
                a1 = fmaf(wreg[9 + j], in9[j], a1);
            }
            u32 w = (u32)f2b(posit_q(fmaxf(a0, 0.f))) | ((u32)f2b(posit_q(fmaxf(a1, 0.f))) << 16);
            *(u32*)&sH1[p * H1S + ocp * 2] = w;
        }
    }

    // conv2 B-frags for THIS WAVE's n-pair only: 18 frags = 72 VGPRs (allocator-friendly)
    __syncthreads();
    int npair = wave & 1, mhalf = wave >> 1;
    bf16x8 bfrag[2][9];
#pragma unroll
    for (int j = 0; j < 2; ++j)
#pragma unroll
        for (int kc = 0; kc < 9; ++kc)
            bfrag[j][kc] = *(const bf16x8*)(w2frag + (((npair * 2 + j) * 9 + kc) * 64 + lane) * 8);
    float cb0 = b2[(npair * 2) * 16 + col];
    float cb1 = b2[(npair * 2 + 1) * 16 + col];
    int poolb0 = ((npair * 2) * 16 + col) * 152;
    int poolb1 = ((npair * 2 + 1) * 16 + col) * 152;

    // phase 2: conv2 MFMA + pool(max) + bias + relu + pq. Wave covers m-tiles mhalf*18..+17, 2 n-tiles.
    for (int t = 0; t < 18; ++t) {
        int mt = mhalf * 18 + t;
        int m = mt * 16 + col;                  // pool-permuted m (A-row = lane&15)
        int pp = m >> 2, wi = m & 3;
        int py = pp / 12, px_ = pp - py * 12;
        int oh = 2 * py + (wi >> 1), ow = 2 * px_ + (wi & 1);
        const u16* ap = &sH1[(oh * 26 + ow) * H1S + quad * 8];
        f32x4 acc0 = {0.f, 0.f, 0.f, 0.f}, acc1 = {0.f, 0.f, 0.f, 0.f};
#pragma unroll
        for (int kc = 0; kc < 9; ++kc) {
            int kh = kc / 3, kw = kc - kh * 3;
            bf16x8 af = *(const bf16x8*)(ap + (kh * 26 + kw) * H1S);  // 1 ds_read_b128 : 2 MFMA
            acc0 = __builtin_amdgcn_mfma_f32_16x16x32_bf16(af, bfrag[0][kc], acc0, 0, 0, 0);
            acc1 = __builtin_amdgcn_mfma_f32_16x16x32_bf16(af, bfrag[1][kc], acc1, 0, 0, 0);
        }
        // C/D: row = quad*4+reg -> lane's 4 regs = one 2x2 pool window; max commutes exactly
        float mx0 = fmaxf(fmaxf(acc0[0], acc0[1]), fmaxf(acc0[2], acc0[3]));
        float mx1 = fmaxf(fmaxf(acc1[0], acc1[1]), fmaxf(acc1[2], acc1[3]));
        sPool[poolb0 + mt * 4 + quad] = f2b(posit_q(fmaxf(mx0 + cb0, 0.f)));
        sPool[poolb1 + mt * 4 + quad] = f2b(posit_q(fmaxf(mx1 + cb1, 0.f)));
    }
    __syncthreads();

    // phase 3: coalesced writeout, c-major (fc1 K layout)
    for (int u = tid; u < 1152; u += 256) {
        int c = u / 18, g = u - c * 18;
        uint4 v = *(const uint4*)&sPool[c * 152 + g * 8];
        *(uint4*)(pooled + (size_t)img * 9216 + c * 144 + g * 8) = v;
    }
}

// ---------- kernel 3: fc1 (M=4096,N=128,K=9216) + bias + relu + pq, fused fc2 ----------
__global__ __launch_bounds__(512, 2) void fc_kernel(const u16* __restrict__ pooled,
    const u16* __restrict__ fc1wq, const float* __restrict__ fc1b,
    const float* __restrict__ fc2wq, const float* __restrict__ fc2b,
    float* __restrict__ out) {
    __shared__ __align__(16) float sAcc[4][16 * 132];
    __shared__ __align__(16) u16 sFc1[16 * 128];
    __shared__ float sW2[1280];
    __shared__ float sB2[16];
    int blk = blockIdx.x, tid = threadIdx.x;
    int wave = tid >> 6, lane = tid & 63;
    int row = lane & 15, quad = lane >> 4;
    int m0 = blk * 16;
    for (int i = tid; i < 1280; i += 512) sW2[i] = fc2wq[i];
    if (tid < 10) sB2[tid] = fc2b[tid];

    const bf16x8* ap = (const bf16x8*)(pooled + (size_t)(m0 + row) * 9216 + wave * 1152) + quad;
    const bf16x8* bp[8];
#pragma unroll
    for (int nt = 0; nt < 8; ++nt)
        bp[nt] = (const bf16x8*)(fc1wq + (size_t)(nt * 16 + row) * 9216 + wave * 1152) + quad;
    f32x4 acc[8];
#pragma unroll
    for (int nt = 0; nt < 8; ++nt) acc[nt] = f32x4{0.f, 0.f, 0.f, 0.f};
#pragma unroll 4
    for (int ks = 0; ks < 36; ++ks) {
        bf16x8 a = ap[ks * 4];
#pragma unroll
        for (int nt = 0; nt < 8; ++nt)
            acc[nt] = __builtin_amdgcn_mfma_f32_16x16x32_bf16(a, bp[nt][ks * 4], acc[nt], 0, 0, 0);
    }
    if (wave < 4) {
#pragma unroll
        for (int nt = 0; nt < 8; ++nt)
#pragma unroll
            for (int r = 0; r < 4; ++r)
                sAcc[wave][(quad * 4 + r) * 132 + nt * 16 + row] = acc[nt][r];
    }
    __syncthreads();
    if (wave >= 4) {
#pragma unroll
        for (int nt = 0; nt < 8; ++nt)
#pragma unroll
            for (int r = 0; r < 4; ++r)
                sAcc[wave - 4][(quad * 4 + r) * 132 + nt * 16 + row] += acc[nt][r];
    }
    __syncthreads();
    for (int e = tid; e < 2048; e += 512) {
        int ml = e >> 7, n = e & 127;
        int o = ml * 132 + n;
        float s = sAcc[0][o] + sAcc[1][o] + sAcc[2][o] + sAcc[3][o];
        sFc1[e] = f2b(posit_q(fmaxf(s + fc1b[n], 0.f)));
    }
    __syncthreads();
    if (tid < 160) {
        int il = tid / 10, oc = tid - il * 10;
        float s = sB2[oc];
        const u16* hp = &sFc1[il * 128];
        const float* wp = &sW2[oc * 128];
#pragma unroll
        for (int k = 0; k < 128; ++k) s = fmaf(b2f(hp[k]), wp[k], s);
        out[(size_t)(m0 + il) * 10 + oc] = s;
    }
}

extern "C" void kernel_launch(void* const* d_in, const int* in_sizes, int n_in,
                              void* d_out, int out_size, void* d_ws, size_t ws_size,
                              hipStream_t stream) {
    const float* x    = (const float*)d_in[0];
    const float* w1   = (const float*)d_in[1];
    const float* b1   = (const float*)d_in[2];
    const float* w2   = (const float*)d_in[3];
    const float* b2   = (const float*)d_in[4];
    const float* fw1  = (const float*)d_in[5];
    const float* fb1  = (const float*)d_in[6];
    const float* fw2  = (const float*)d_in[7];
    const float* fb2  = (const float*)d_in[8];
    float* out = (float*)d_out;

    char* ws = (char*)d_ws;
    float* w1q     = (float*)(ws + 0);           // 1152 B
    float* fc2wq   = (float*)(ws + 1280);        // 5120 B
    u16*   w2frag  = (u16*)(ws + 6400);          // 36864 B
    u16*   fc1wq   = (u16*)(ws + 43520);         // 2359296 B
    u16*   pooled  = (u16*)(ws + 2402816);       // 75497472 B, [img][c*144 + y*12 + x] bf16
    // total ~78 MB

    prep_kernel<<<4608, 256, 0, stream>>>(w1, w2, fw1, fw2, w1q, w2frag, fc1wq, fc2wq);
    conv_fused_kernel<<<4096, 256, 0, stream>>>(x, w1q, b1, w2frag, b2, pooled);
    fc_kernel<<<256, 512, 0, stream>>>(pooled, fc1wq, fb1, fc2wq, fb2, out);
}

// Round 7
// 297.781 us; speedup vs baseline: 1.1527x; 1.1527x over previous
//
#include <hip/hip_runtime.h>

using u16 = unsigned short;
using u32 = unsigned int;
typedef __attribute__((ext_vector_type(8))) short bf16x8;
typedef __attribute__((ext_vector_type(4))) float f32x4;

// ---------- posit(8,1) round-to-nearest (float core, verified bit-exact on HW) ----------
__device__ __forceinline__ float posit_q(float x) {
    float a = __builtin_fabsf(x);
    u32 u = __float_as_uint(a);
    int logx = (int)(u >> 23) - 127;
    logx = logx < -60 ? -60 : (logx > 60 ? 60 : logx);
    float frac = __uint_as_float((u & 0x007fffffu) | 0x3f800000u);  // [1,2)
    int k = logx >> 1;                            // floor(logx/2), es=1
    int rl = (k >= 0) ? (k + 2) : (1 - k);        // regime length
    int fb = 6 - rl; fb = fb < 0 ? 0 : fb;        // fraction bits, <=4
    float step = (float)(1 << fb);
    float q = rintf(frac * step) * __uint_as_float((u32)(127 + logx - fb) << 23);
    q = fminf(fmaxf(q, 0x1p-12f), 0x1p12f);
    return (a > 0.0f) ? copysignf(q, x) : 0.0f;
}

__device__ __forceinline__ float b2f(u16 v) { return __uint_as_float((u32)v << 16); }
__device__ __forceinline__ u16 f2b(float f) { return (u16)(__float_as_uint(f) >> 16); }  // exact for posit values

// ---------- kernel 1: quantize small weights (w1, w2frag, fc2) ----------
// w2frag layout: [nt(4)][kc(9)][lane(64)][e(8)]; B[k][n], k=kc*32+(lane>>4)*8+e (ci), n=nt*16+(lane&15).
__global__ __launch_bounds__(256) void prep_kernel(
    const float* __restrict__ w1, const float* __restrict__ w2,
    const float* __restrict__ fw2,
    float* __restrict__ w1q, u16* __restrict__ w2frag, float* __restrict__ fc2wq) {
    int i = blockIdx.x * 256 + threadIdx.x;
    if (i < 288)  w1q[i]   = posit_q(w1[i]);
    if (i < 1280) fc2wq[i] = posit_q(fw2[i]);
    if (i < 18432) {
        int e = i & 7, lane = (i >> 3) & 63, c9 = i >> 9;
        int kc = c9 % 9, nt = c9 / 9;
        int n = nt * 16 + (lane & 15);
        int ci = ((lane >> 4) << 3) + e;
        w2frag[i] = f2b(posit_q(w2[n * 288 + ci * 9 + kc]));  // w2 flat [n][ci][kh][kw]
    }
}

// ---------- kernel 2: fused pq(x) + conv1 + relu + pq + conv2(MFMA) + pool + bias + relu + pq ----------
// 512 threads = 8 waves per image-block; LDS ~64 KB -> 2 blocks/CU -> 4 waves/SIMD.
// sH1 stored as 4 ci-planes: plane q = [pixel(676)][8 u16], plane stride 5416 u16
// (10832 B; word-stride 2708 ≡ 20 mod 32 -> +5 bank-cluster dephase per plane).
// A-read (ds_read_b128): cluster = (p + 5*quad) mod 8, uniform -> conflict-free.
#define PLS 5416
__global__ __launch_bounds__(512, 4) void conv_fused_kernel(
    const float* __restrict__ x, const float* __restrict__ w1q, const float* __restrict__ b1,
    const u16* __restrict__ w2frag, const float* __restrict__ b2,
    const float* __restrict__ fw1, u16* __restrict__ fc1wq, u16* __restrict__ pooled) {
    __shared__ __align__(16) float sX[784];           // 3136 B
    __shared__ __align__(16) u16 sH1[4 * PLS];        // 43328 B
    __shared__ __align__(16) u16 sPool[64 * 152];     // 19456 B  (total 65920 B -> 2 blocks/CU)
    int img = blockIdx.x, tid = threadIdx.x;
    int wave = tid >> 6, lane = tid & 63;
    int col = lane & 15, quad = lane >> 4;

    // phase 0: pq input image -> LDS; also quantize this block's slice of fc1 weights (global)
    for (int i = tid; i < 784; i += 512) sX[i] = posit_q(x[(size_t)img * 784 + i]);
    if (tid < 288) fc1wq[(size_t)img * 288 + tid] = f2b(posit_q(fw1[(size_t)img * 288 + tid]));

    // conv1 weights for this thread's oc pair (registers)
    int ocp = tid & 15;
    float wreg[18];
#pragma unroll
    for (int j = 0; j < 18; ++j) wreg[j] = w1q[ocp * 18 + j];
    float bias0 = b1[ocp * 2], bias1 = b1[ocp * 2 + 1];

    __syncthreads();

    // phase 1: conv1 (+bias+relu+pq) -> sH1 planes. thread = (pgrp = tid>>4 in 0..31, ocp).
    // oc pair {2*ocp, 2*ocp+1} lives in plane ocp>>2 at element 2*(ocp&3) -> one u32 write.
    int pgrp = tid >> 4;
    u16* h1dst = &sH1[(ocp >> 2) * PLS + 2 * (ocp & 3)];
    for (int it = 0; it < 22; ++it) {
        int p = it * 32 + pgrp;
        if (p < 676) {
            int y = p / 26, xx = p - y * 26;
            const float* px = &sX[y * 28 + xx];
            float in9[9];
#pragma unroll
            for (int r = 0; r < 3; ++r)
#pragma unroll
                for (int c = 0; c < 3; ++c) in9[r * 3 + c] = px[r * 28 + c];
            float a0 = bias0, a1 = bias1;
#pragma unroll
            for (int j = 0; j < 9; ++j) {
                a0 = fmaf(wreg[j], in9[j], a0);
                a1 = fmaf(wreg[9 + j], in9[j], a1);
            }
            u32 w = (u32)f2b(posit_q(fmaxf(a0, 0.f))) | ((u32)f2b(posit_q(fmaxf(a1, 0.f))) << 16);
            *(u32*)&h1dst[p * 8] = w;
        }
    }

    // conv2 B-frags for this wave's n-pair: 18 frags = 72 VGPRs (resident, verified R6)
    __syncthreads();
    int npair = wave & 1, mq = wave >> 1;
    bf16x8 bfrag[2][9];
#pragma unroll
    for (int j = 0; j < 2; ++j)
#pragma unroll
        for (int kc = 0; kc < 9; ++kc)
            bfrag[j][kc] = *(const bf16x8*)(w2frag + (((npair * 2 + j) * 9 + kc) * 64 + lane) * 8);
    float cb0 = b2[(npair * 2) * 16 + col];
    float cb1 = b2[(npair * 2 + 1) * 16 + col];
    int poolb0 = ((npair * 2) * 16 + col) * 152;
    int poolb1 = ((npair * 2 + 1) * 16 + col) * 152;
    const u16* aplane = &sH1[quad * PLS];

    // phase 2: conv2 MFMA + pool(max) + bias + relu + pq. Wave: m-tiles mq*9..mq*9+8, 2 n-tiles.
    for (int t = 0; t < 9; ++t) {
        int mt = mq * 9 + t;
        int m = mt * 16 + col;                  // pool-permuted m (A-row = lane&15)
        int pp = m >> 2, wi = m & 3;
        int py = pp / 12, px_ = pp - py * 12;
        int oh = 2 * py + (wi >> 1), ow = 2 * px_ + (wi & 1);
        const u16* ap = aplane + (oh * 26 + ow) * 8;
        f32x4 acc0 = {0.f, 0.f, 0.f, 0.f}, acc1 = {0.f, 0.f, 0.f, 0.f};
#pragma unroll
        for (int kc = 0; kc < 9; ++kc) {
            int kh = kc / 3, kw = kc - kh * 3;
            bf16x8 af = *(const bf16x8*)(ap + (kh * 26 + kw) * 8);  // conflict-free ds_read_b128
            acc0 = __builtin_amdgcn_mfma_f32_16x16x32_bf16(af, bfrag[0][kc], acc0, 0, 0, 0);
            acc1 = __builtin_amdgcn_mfma_f32_16x16x32_bf16(af, bfrag[1][kc], acc1, 0, 0, 0);
        }
        // C/D: row = quad*4+reg -> lane's 4 regs = one 2x2 pool window; max commutes exactly
        float mx0 = fmaxf(fmaxf(acc0[0], acc0[1]), fmaxf(acc0[2], acc0[3]));
        float mx1 = fmaxf(fmaxf(acc1[0], acc1[1]), fmaxf(acc1[2], acc1[3]));
        sPool[poolb0 + mt * 4 + quad] = f2b(posit_q(fmaxf(mx0 + cb0, 0.f)));
        sPool[poolb1 + mt * 4 + quad] = f2b(posit_q(fmaxf(mx1 + cb1, 0.f)));
    }
    __syncthreads();

    // phase 3: coalesced writeout, c-major (fc1 K layout)
    for (int u = tid; u < 1152; u += 512) {
        int c = u / 18, g = u - c * 18;
        uint4 v = *(const uint4*)&sPool[c * 152 + g * 8];
        *(uint4*)(pooled + (size_t)img * 9216 + c * 144 + g * 8) = v;
    }
}

// ---------- kernel 3: fc1 (M=4096,N=128,K=9216) + bias + relu + pq, fused fc2 ----------
__global__ __launch_bounds__(512, 2) void fc_kernel(const u16* __restrict__ pooled,
    const u16* __restrict__ fc1wq, const float* __restrict__ fc1b,
    const float* __restrict__ fc2wq, const float* __restrict__ fc2b,
    float* __restrict__ out) {
    __shared__ __align__(16) float sAcc[4][16 * 132];
    __shared__ __align__(16) u16 sFc1[16 * 128];
    __shared__ float sW2[1280];
    __shared__ float sB2[16];
    int blk = blockIdx.x, tid = threadIdx.x;
    int wave = tid >> 6, lane = tid & 63;
    int row = lane & 15, quad = lane >> 4;
    int m0 = blk * 16;
    for (int i = tid; i < 1280; i += 512) sW2[i] = fc2wq[i];
    if (tid < 10) sB2[tid] = fc2b[tid];

    const bf16x8* ap = (const bf16x8*)(pooled + (size_t)(m0 + row) * 9216 + wave * 1152) + quad;
    const bf16x8* bp[8];
#pragma unroll
    for (int nt = 0; nt < 8; ++nt)
        bp[nt] = (const bf16x8*)(fc1wq + (size_t)(nt * 16 + row) * 9216 + wave * 1152) + quad;
    f32x4 acc[8];
#pragma unroll
    for (int nt = 0; nt < 8; ++nt) acc[nt] = f32x4{0.f, 0.f, 0.f, 0.f};
#pragma unroll 4
    for (int ks = 0; ks < 36; ++ks) {
        bf16x8 a = ap[ks * 4];
#pragma unroll
        for (int nt = 0; nt < 8; ++nt)
            acc[nt] = __builtin_amdgcn_mfma_f32_16x16x32_bf16(a, bp[nt][ks * 4], acc[nt], 0, 0, 0);
    }
    if (wave < 4) {
#pragma unroll
        for (int nt = 0; nt < 8; ++nt)
#pragma unroll
            for (int r = 0; r < 4; ++r)
                sAcc[wave][(quad * 4 + r) * 132 + nt * 16 + row] = acc[nt][r];
    }
    __syncthreads();
    if (wave >= 4) {
#pragma unroll
        for (int nt = 0; nt < 8; ++nt)
#pragma unroll
            for (int r = 0; r < 4; ++r)
                sAcc[wave - 4][(quad * 4 + r) * 132 + nt * 16 + row] += acc[nt][r];
    }
    __syncthreads();
    for (int e = tid; e < 2048; e += 512) {
        int ml = e >> 7, n = e & 127;
        int o = ml * 132 + n;
        float s = sAcc[0][o] + sAcc[1][o] + sAcc[2][o] + sAcc[3][o];
        sFc1[e] = f2b(posit_q(fmaxf(s + fc1b[n], 0.f)));
    }
    __syncthreads();
    if (tid < 160) {
        int il = tid / 10, oc = tid - il * 10;
        float s = sB2[oc];
        const u16* hp = &sFc1[il * 128];
        const float* wp = &sW2[oc * 128];
#pragma unroll
        for (int k = 0; k < 128; ++k) s = fmaf(b2f(hp[k]), wp[k], s);
        out[(size_t)(m0 + il) * 10 + oc] = s;
    }
}

extern "C" void kernel_launch(void* const* d_in, const int* in_sizes, int n_in,
                              void* d_out, int out_size, void* d_ws, size_t ws_size,
                              hipStream_t stream) {
    const float* x    = (const float*)d_in[0];
    const float* w1   = (const float*)d_in[1];
    const float* b1   = (const float*)d_in[2];
    const float* w2   = (const float*)d_in[3];
    const float* b2   = (const float*)d_in[4];
    const float* fw1  = (const float*)d_in[5];
    const float* fb1  = (const float*)d_in[6];
    const float* fw2  = (const float*)d_in[7];
    const float* fb2  = (const float*)d_in[8];
    float* out = (float*)d_out;

    char* ws = (char*)d_ws;
    float* w1q     = (float*)(ws + 0);           // 1152 B
    float* fc2wq   = (float*)(ws + 1280);        // 5120 B
    u16*   w2frag  = (u16*)(ws + 6400);          // 36864 B
    u16*   fc1wq   = (u16*)(ws + 43520);         // 2359296 B
    u16*   pooled  = (u16*)(ws + 2402816);       // 75497472 B, [img][c*144 + y*12 + x] bf16
    // total ~78 MB

    prep_kernel<<<72, 256, 0, stream>>>(w1, w2, fw2, w1q, w2frag, fc2wq);
    conv_fused_kernel<<<4096, 512, 0, stream>>>(x, w1q, b1, w2frag, b2, fw1, fc1wq, pooled);
    fc_kernel<<<256, 512, 0, stream>>>(pooled, fc1wq, fb1, fc2wq, fb2, out);
}

// Round 8
// 270.497 us; speedup vs baseline: 1.2690x; 1.1009x over previous
//
#include <hip/hip_runtime.h>

using u16 = unsigned short;
using u32 = unsigned int;
typedef __attribute__((ext_vector_type(8))) short bf16x8;
typedef __attribute__((ext_vector_type(4))) float f32x4;

// ---------- posit(8,1) round-to-nearest (float core, verified bit-exact on HW) ----------
__device__ __forceinline__ float posit_q(float x) {
    float a = __builtin_fabsf(x);
    u32 u = __float_as_uint(a);
    int logx = (int)(u >> 23) - 127;
    logx = logx < -60 ? -60 : (logx > 60 ? 60 : logx);
    float frac = __uint_as_float((u & 0x007fffffu) | 0x3f800000u);  // [1,2)
    int k = logx >> 1;                            // floor(logx/2), es=1
    int rl = (k >= 0) ? (k + 2) : (1 - k);        // regime length
    int fb = 6 - rl; fb = fb < 0 ? 0 : fb;        // fraction bits, <=4
    float step = (float)(1 << fb);
    float q = rintf(frac * step) * __uint_as_float((u32)(127 + logx - fb) << 23);
    q = fminf(fmaxf(q, 0x1p-12f), 0x1p12f);
    return (a > 0.0f) ? copysignf(q, x) : 0.0f;
}

__device__ __forceinline__ float b2f(u16 v) { return __uint_as_float((u32)v << 16); }
__device__ __forceinline__ u16 f2b(float f) { return (u16)(__float_as_uint(f) >> 16); }  // exact for posit values

// ---------- Dekker-LUT posit quantizer (exact RNE onto the posit grid) ----------
// LUT[e8] = 1.5*2^(23+e-fb(e)) for |e|<=12 else 0. q = (x+c)-c rounds x (RNE, hardware)
// onto grid 2^(e-fb); exact incl. binade promotion & ties-to-even (same quantity jnp.round
// rounds). c=0 -> q=x; med3 clip then yields the correct saturation (minpos/maxpos).
__device__ __forceinline__ void lut_init(int tid, float* lut) {
    if (tid < 256) {
        int e = tid - 127;
        float m = 0.f;
        if (e >= -12 && e <= 12) {
            int k = e >> 1;
            int rl = max(k + 2, 1 - k);
            int fb = max(6 - rl, 0);
            m = __uint_as_float((u32)(150 + e - fb) << 23) * 1.5f;  // 1.5*2^(23+e-fb)
        }
        lut[tid] = m;
    }
}
__device__ __forceinline__ u32 pq_pos_raw(float x, const float* __restrict__ lut) {  // x >= 0
    u32 u = __float_as_uint(x);
    float c = lut[u >> 23];
    float q = (x + c) - c;
    q = fminf(fmaxf(q, 0x1p-12f), 0x1p12f);
    return u == 0u ? 0u : __float_as_uint(q);
}

// ---------- kernel 1: quantize small weights (w1, w2frag, fc2) ----------
// w2frag layout: [nt(4)][kc(9)][lane(64)][e(8)]; B[k][n], k=kc*32+(lane>>4)*8+e (ci), n=nt*16+(lane&15).
__global__ __launch_bounds__(256) void prep_kernel(
    const float* __restrict__ w1, const float* __restrict__ w2,
    const float* __restrict__ fw2,
    float* __restrict__ w1q, u16* __restrict__ w2frag, float* __restrict__ fc2wq) {
    int i = blockIdx.x * 256 + threadIdx.x;
    if (i < 288)  w1q[i]   = posit_q(w1[i]);
    if (i < 1280) fc2wq[i] = posit_q(fw2[i]);
    if (i < 18432) {
        int e = i & 7, lane = (i >> 3) & 63, c9 = i >> 9;
        int kc = c9 % 9, nt = c9 / 9;
        int n = nt * 16 + (lane & 15);
        int ci = ((lane >> 4) << 3) + e;
        w2frag[i] = f2b(posit_q(w2[n * 288 + ci * 9 + kc]));  // w2 flat [n][ci][kh][kw]
    }
}

// ---------- kernel 2: fused pq(x) + conv1 + relu + pq + conv2(MFMA) + pool + bias + relu + pq ----------
// 512 threads = 8 waves per image-block; LDS ~65 KB -> 2 blocks/CU -> 4 waves/SIMD.
// sH1: 4 ci-planes [pixel(676)][8 u16], plane stride 5416 u16.
#define PLS 5416
__global__ __launch_bounds__(512, 4) void conv_fused_kernel(
    const float* __restrict__ x, const float* __restrict__ w1q, const float* __restrict__ b1,
    const u16* __restrict__ w2frag, const float* __restrict__ b2,
    const float* __restrict__ fw1, u16* __restrict__ fc1wq, u16* __restrict__ pooled) {
    __shared__ __align__(16) float sX[784];           // 3136 B
    __shared__ __align__(16) u16 sH1[4 * PLS];        // 43328 B
    __shared__ __align__(16) u16 sPool[64 * 152];     // 19456 B
    __shared__ float sLut[256];                       // 1024 B (total 66944 B -> 2 blocks/CU)
    int img = blockIdx.x, tid = threadIdx.x;
    int wave = tid >> 6, lane = tid & 63;
    int col = lane & 15, quad = lane >> 4;

    lut_init(tid, sLut);

    // phase 0: pq input image -> LDS; also quantize this block's slice of fc1 weights (global)
    for (int i = tid; i < 784; i += 512) sX[i] = posit_q(x[(size_t)img * 784 + i]);
    if (tid < 288) fc1wq[(size_t)img * 288 + tid] = f2b(posit_q(fw1[(size_t)img * 288 + tid]));

    // conv1 weights for this thread's oc pair (registers)
    int ocp = tid & 15;
    float wreg[18];
#pragma unroll
    for (int j = 0; j < 18; ++j) wreg[j] = w1q[ocp * 18 + j];
    float bias0 = b1[ocp * 2], bias1 = b1[ocp * 2 + 1];

    __syncthreads();

    // phase 1: conv1 (+bias+relu+pq) -> sH1 planes. thread = (pgrp = tid>>4 in 0..31, ocp).
    int pgrp = tid >> 4;
    u16* h1dst = &sH1[(ocp >> 2) * PLS + 2 * (ocp & 3)];
    for (int it = 0; it < 22; ++it) {
        int p = it * 32 + pgrp;
        if (p < 676) {
            int y = p / 26, xx = p - y * 26;
            const float* px = &sX[y * 28 + xx];
            float in9[9];
#pragma unroll
            for (int r = 0; r < 3; ++r)
#pragma unroll
                for (int c = 0; c < 3; ++c) in9[r * 3 + c] = px[r * 28 + c];
            float a0 = bias0, a1 = bias1;
#pragma unroll
            for (int j = 0; j < 9; ++j) {
                a0 = fmaf(wreg[j], in9[j], a0);
                a1 = fmaf(wreg[9 + j], in9[j], a1);
            }
            u32 r0 = pq_pos_raw(fmaxf(a0, 0.f), sLut);
            u32 r1 = pq_pos_raw(fmaxf(a1, 0.f), sLut);
            *(u32*)&h1dst[p * 8] = (r0 >> 16) | (r1 & 0xFFFF0000u);
        }
    }

    // conv2 B-frags for this wave's n-pair: 18 frags = 72 VGPRs (resident, verified R6)
    __syncthreads();
    int npair = wave & 1, mq = wave >> 1;
    bf16x8 bfrag[2][9];
#pragma unroll
    for (int j = 0; j < 2; ++j)
#pragma unroll
        for (int kc = 0; kc < 9; ++kc)
            bfrag[j][kc] = *(const bf16x8*)(w2frag + (((npair * 2 + j) * 9 + kc) * 64 + lane) * 8);
    float cb0 = b2[(npair * 2) * 16 + col];
    float cb1 = b2[(npair * 2 + 1) * 16 + col];
    int poolb0 = ((npair * 2) * 16 + col) * 152;
    int poolb1 = ((npair * 2 + 1) * 16 + col) * 152;
    const u16* aplane = &sH1[quad * PLS];

    // phase 2: conv2 MFMA + pool(max) + bias + relu + pq. Wave: m-tiles mq*9..mq*9+8, 2 n-tiles.
    for (int t = 0; t < 9; ++t) {
        int mt = mq * 9 + t;
        int m = mt * 16 + col;                  // pool-permuted m (A-row = lane&15)
        int pp = m >> 2, wi = m & 3;
        int py = pp / 12, px_ = pp - py * 12;
        int oh = 2 * py + (wi >> 1), ow = 2 * px_ + (wi & 1);
        const u16* ap = aplane + (oh * 26 + ow) * 8;
        f32x4 acc0 = {0.f, 0.f, 0.f, 0.f}, acc1 = {0.f, 0.f, 0.f, 0.f};
#pragma unroll
        for (int kc = 0; kc < 9; ++kc) {
            int kh = kc / 3, kw = kc - kh * 3;
            bf16x8 af = *(const bf16x8*)(ap + (kh * 26 + kw) * 8);
            acc0 = __builtin_amdgcn_mfma_f32_16x16x32_bf16(af, bfrag[0][kc], acc0, 0, 0, 0);
            acc1 = __builtin_amdgcn_mfma_f32_16x16x32_bf16(af, bfrag[1][kc], acc1, 0, 0, 0);
        }
        // C/D: row = quad*4+reg -> lane's 4 regs = one 2x2 pool window; max commutes exactly
        float mx0 = fmaxf(fmaxf(acc0[0], acc0[1]), fmaxf(acc0[2], acc0[3]));
        float mx1 = fmaxf(fmaxf(acc1[0], acc1[1]), fmaxf(acc1[2], acc1[3]));
        sPool[poolb0 + mt * 4 + quad] = (u16)(pq_pos_raw(fmaxf(mx0 + cb0, 0.f), sLut) >> 16);
        sPool[poolb1 + mt * 4 + quad] = (u16)(pq_pos_raw(fmaxf(mx1 + cb1, 0.f), sLut) >> 16);
    }
    __syncthreads();

    // phase 3: coalesced writeout, c-major (fc1 K layout)
    for (int u = tid; u < 1152; u += 512) {
        int c = u / 18, g = u - c * 18;
        uint4 v = *(const uint4*)&sPool[c * 152 + g * 8];
        *(uint4*)(pooled + (size_t)img * 9216 + c * 144 + g * 8) = v;
    }
}

// ---------- kernel 3: fc1 (M=4096,N=128,K=9216) + bias + relu + pq, fused fc2 ----------
__global__ __launch_bounds__(512, 2) void fc_kernel(const u16* __restrict__ pooled,
    const u16* __restrict__ fc1wq, const float* __restrict__ fc1b,
    const float* __restrict__ fc2wq, const float* __restrict__ fc2b,
    float* __restrict__ out) {
    __shared__ __align__(16) float sAcc[4][16 * 132];
    __shared__ __align__(16) u16 sFc1[16 * 128];
    __shared__ float sW2[1280];
    __shared__ float sB2[16];
    __shared__ float sLut[256];
    int blk = blockIdx.x, tid = threadIdx.x;
    int wave = tid >> 6, lane = tid & 63;
    int row = lane & 15, quad = lane >> 4;
    int m0 = blk * 16;
    lut_init(tid, sLut);
    for (int i = tid; i < 1280; i += 512) sW2[i] = fc2wq[i];
    if (tid < 10) sB2[tid] = fc2b[tid];

    const bf16x8* ap = (const bf16x8*)(pooled + (size_t)(m0 + row) * 9216 + wave * 1152) + quad;
    const bf16x8* bp[8];
#pragma unroll
    for (int nt = 0; nt < 8; ++nt)
        bp[nt] = (const bf16x8*)(fc1wq + (size_t)(nt * 16 + row) * 9216 + wave * 1152) + quad;
    f32x4 acc[8];
#pragma unroll
    for (int nt = 0; nt < 8; ++nt) acc[nt] = f32x4{0.f, 0.f, 0.f, 0.f};
#pragma unroll 4
    for (int ks = 0; ks < 36; ++ks) {
        bf16x8 a = ap[ks * 4];
#pragma unroll
        for (int nt = 0; nt < 8; ++nt)
            acc[nt] = __builtin_amdgcn_mfma_f32_16x16x32_bf16(a, bp[nt][ks * 4], acc[nt], 0, 0, 0);
    }
    if (wave < 4) {
#pragma unroll
        for (int nt = 0; nt < 8; ++nt)
#pragma unroll
            for (int r = 0; r < 4; ++r)
                sAcc[wave][(quad * 4 + r) * 132 + nt * 16 + row] = acc[nt][r];
    }
    __syncthreads();
    if (wave >= 4) {
#pragma unroll
        for (int nt = 0; nt < 8; ++nt)
#pragma unroll
            for (int r = 0; r < 4; ++r)
                sAcc[wave - 4][(quad * 4 + r) * 132 + nt * 16 + row] += acc[nt][r];
    }
    __syncthreads();
    for (int e = tid; e < 2048; e += 512) {
        int ml = e >> 7, n = e & 127;
        int o = ml * 132 + n;
        float s = sAcc[0][o] + sAcc[1][o] + sAcc[2][o] + sAcc[3][o];
        sFc1[e] = (u16)(pq_pos_raw(fmaxf(s + fc1b[n], 0.f), sLut) >> 16);
    }
    __syncthreads();
    if (tid < 160) {
        int il = tid / 10, oc = tid - il * 10;
        float s = sB2[oc];
        const u16* hp = &sFc1[il * 128];
        const float* wp = &sW2[oc * 128];
#pragma unroll
        for (int k = 0; k < 128; ++k) s = fmaf(b2f(hp[k]), wp[k], s);
        out[(size_t)(m0 + il) * 10 + oc] = s;
    }
}

extern "C" void kernel_launch(void* const* d_in, const int* in_sizes, int n_in,
                              void* d_out, int out_size, void* d_ws, size_t ws_size,
                              hipStream_t stream) {
    const float* x    = (const float*)d_in[0];
    const float* w1   = (const float*)d_in[1];
    const float* b1   = (const float*)d_in[2];
    const float* w2   = (const float*)d_in[3];
    const float* b2   = (const float*)d_in[4];
    const float* fw1  = (const float*)d_in[5];
    const float* fb1  = (const float*)d_in[6];
    const float* fw2  = (const float*)d_in[7];
    const float* fb2  = (const float*)d_in[8];
    float* out = (float*)d_out;

    char* ws = (char*)d_ws;
    float* w1q     = (float*)(ws + 0);           // 1152 B
    float* fc2wq   = (float*)(ws + 1280);        // 5120 B
    u16*   w2frag  = (u16*)(ws + 6400);          // 36864 B
    u16*   fc1wq   = (u16*)(ws + 43520);         // 2359296 B
    u16*   pooled  = (u16*)(ws + 2402816);       // 75497472 B, [img][c*144 + y*12 + x] bf16
    // total ~78 MB

    prep_kernel<<<72, 256, 0, stream>>>(w1, w2, fw2, w1q, w2frag, fc2wq);
    conv_fused_kernel<<<4096, 512, 0, stream>>>(x, w1q, b1, w2frag, b2, fw1, fc1wq, pooled);
    fc_kernel<<<256, 512, 0, stream>>>(pooled, fc1wq, fb1, fc2wq, fb2, out);
}